// Round 24
// baseline (102.229 us; speedup 1.0000x reference)
//
#include <hip/hip_runtime.h>
#include <stdint.h>

#define K_DIM 4096
#define N_DIM 11008
#define M_DIM 256
#define MN ((size_t)M_DIM * N_DIM)

typedef uint32_t u32;
using frag_ab = __attribute__((ext_vector_type(8))) short;   // 8 bf16
using frag_cd = __attribute__((ext_vector_type(4))) float;   // 4 f32
using u32x4   = __attribute__((ext_vector_type(4))) uint32_t;

typedef __attribute__((address_space(3))) const char lds_cc;

#define DSR128(dst, addr, off)                                       \
    asm volatile("ds_read_b128 %0, %1 offset:" #off                  \
                 : "=&v"(dst) : "v"(addr))
#define LGKM(n) do { asm volatile("s_waitcnt lgkmcnt(" #n ")" ::: "memory"); \
                     __builtin_amdgcn_sched_barrier(0); } while (0)
#define VMW(n) asm volatile("s_waitcnt vmcnt(" #n ")" ::: "memory")

__device__ __forceinline__ u32 f2bf_rn(float f) {
    u32 u = __builtin_bit_cast(u32, f);
    return (u + 0x7FFFu + ((u >> 16) & 1u)) >> 16;   // round-to-nearest-even
}
__device__ __forceinline__ float bf2f(u32 b) {
    return __builtin_bit_cast(float, b << 16);
}
__device__ __forceinline__ void gll16(const void* g, void* l) {
    __builtin_amdgcn_global_load_lds(
        (const __attribute__((address_space(1))) u32*)g,
        (__attribute__((address_space(3))) u32*)l, 16, 0, 0);
}

// bf16(32+v) = 0x4200 | (v<<2); q*0x4004 = q<<14|q<<2 -> packed bf16x2.
#define BFCVT(q) ((u32)((__mul24((int)(q), 0x4004) & 0x003C003C) | 0x42004200))

// Kernel 0: zero the 172 completion counters (every launch -> replay-safe).
__global__ __launch_bounds__(256) void init_kernel(u32* __restrict__ cnt) {
    if (threadIdx.x < 172) cnt[threadIdx.x] = 0;
}

// Kernel 1: x f32 -> bf16 (RN) + per-row sums of the ROUNDED values.
__global__ __launch_bounds__(256) void prep_kernel(const float* __restrict__ x,
                                                   ushort* __restrict__ xbf,
                                                   float* __restrict__ rowsum) {
    const int row = blockIdx.x;
    const int tid = threadIdx.x;
    const float* xr = x + (size_t)row * K_DIM;
    ushort* br = xbf + (size_t)row * K_DIM;
    float s = 0.0f;
#pragma unroll
    for (int p = 0; p < 4; ++p) {
        int i = p * 1024 + tid * 4;
        float4 v = *reinterpret_cast<const float4*>(xr + i);
        u32 b0 = f2bf_rn(v.x), b1 = f2bf_rn(v.y), b2 = f2bf_rn(v.z), b3 = f2bf_rn(v.w);
        uint2 o;
        o.x = b0 | (b1 << 16);
        o.y = b2 | (b3 << 16);
        *reinterpret_cast<uint2*>(br + i) = o;
        s += bf2f(b0) + bf2f(b1) + bf2f(b2) + bf2f(b3);
    }
#pragma unroll
    for (int off = 32; off > 0; off >>= 1) s += __shfl_down(s, off, 64);
    __shared__ float wsum[4];
    if ((tid & 63) == 0) wsum[tid >> 6] = s;
    __syncthreads();
    if (tid == 0) rowsum[row] = wsum[0] + wsum[1] + wsum[2] + wsum[3];
}

// Kernel 2: r23 gemm (single barrier, depth-1, b128 B via col-group frags,
// split-K=4, grid 688).  mode 2: fused reduction -- all splits write bf16
// partial slot sp; last-arriving block of each (nb,mb) group sums the 4
// slots in FIXED order (deterministic) + rank-1 correction -> out.
__global__ __launch_bounds__(256, 3) void gemm_kernel(const int* __restrict__ qw,
                                                      const float* __restrict__ scales,
                                                      const float* __restrict__ zeroes,
                                                      const ushort* __restrict__ xbf,
                                                      const float* __restrict__ rowsum,
                                                      float* __restrict__ out,
                                                      ushort* __restrict__ partial,
                                                      u32* __restrict__ cnt,
                                                      int mode) {
    // A tile: [m 0..127][chunk 0..3 of 16B], stored chunk' = chunk ^ ((m>>1)&3)
    // B tile: chunk ci = row*32 + wn*16 + l4 holds B[row][wn*64+4*l4 .. +3]
    __shared__ uint4 Alds[3][512];    // 3 x 8 KB
    __shared__ u32   Blds[3][2048];   // 3 x 8 KB
    __shared__ u32   s_done;

    const u32* qwu = (const u32*)qw;
    const int tid  = threadIdx.x;
    const int lane = tid & 63;
    const int wid  = tid >> 6;
    const int l4   = lane & 15;
    const int c    = lane >> 4;

    // XCD-bijective swizzle (688 = 8*86): the 8 blocks (2mb x 4sp) of one
    // n-strip are consecutive wg -> same XCD L2 (partials stay L2-hot).
    const int orig = blockIdx.x;
    int nb, mb, sp, NTt;
    if (mode != 0) {
        int wg = (orig & 7) * 86 + (orig >> 3);
        nb = wg >> 3; sp = (wg >> 1) & 3; mb = wg & 1; NTt = 32;
    } else {
        nb = orig >> 1; mb = orig & 1; sp = 0; NTt = 128;
    }
    const int n0 = nb * 128;
    const int m0 = mb * 128;
    const int wm = wid >> 1;
    const int wn = wid & 1;

    // ---- A staging (r22-verified pre-swizzle)
    const ushort* asrc[2];
#pragma unroll
    for (int j = 0; j < 2; ++j)
        asrc[j] = xbf + (size_t)(m0 + j * 64 + wid * 16 + (lane >> 2)) * K_DIM +
                  sp * 1024 + 8 * ((lane & 3) ^ ((lane >> 3) & 3));
    // ---- B staging (r23-verified): chunk ci = r*256 + wid*64 + lane
    const u32* bsrc[2];
#pragma unroll
    for (int r = 0; r < 2; ++r)
        bsrc[r] = qwu + (size_t)(sp * 512 + r * 8 + wid * 2 + (lane >> 5)) * N_DIM +
                  n0 + ((lane >> 4) & 1) * 64 + 4 * (lane & 15);

    // ---- LDS read byte-offsets
    const u32 aoff = (u32)((wm * 64 + l4) * 64 + ((c ^ ((l4 >> 1) & 3)) << 4));
    const u32 boff = (u32)(c * 2048 + wn * 256 + l4 * 16);   // p stride = 512B

    frag_cd acc[4][4];   // [mf][col-group j]
#pragma unroll
    for (int i = 0; i < 4; ++i)
#pragma unroll
        for (int j = 0; j < 4; ++j)
            acc[i][j] = (frag_cd){0.f, 0.f, 0.f, 0.f};

    auto stage = [&](int t, int buf) {      // 4 x global_load_lds(16B)
#pragma unroll
        for (int j = 0; j < 2; ++j)
            gll16(asrc[j] + (size_t)t * 32, &Alds[buf][j * 256 + wid * 64]);
#pragma unroll
        for (int r = 0; r < 2; ++r)
            gll16(bsrc[r] + (size_t)t * 16 * N_DIM,
                  &Blds[buf][(r * 256 + wid * 64) * 4]);
    };

    auto compute = [&](int buf) {
        lds_cc* Ab = (lds_cc*)&Alds[buf][0];
        lds_cc* Bb = (lds_cc*)&Blds[buf][0];
        u32x4 bqp[4];
        DSR128(bqp[0], Bb + boff, 0);
        DSR128(bqp[1], Bb + boff, 512);
        DSR128(bqp[2], Bb + boff, 1024);
        DSR128(bqp[3], Bb + boff, 1536);
        frag_ab afr[4];
        DSR128(afr[0], Ab + aoff, 0);
        DSR128(afr[1], Ab + aoff, 1024);
        DSR128(afr[2], Ab + aoff, 2048);
        DSR128(afr[3], Ab + aoff, 3072);
        LGKM(4);   // B0..3 landed (in-order DS completion)
        union { frag_ab f; u32 u[4]; } bb[4];
#pragma unroll
        for (int j = 0; j < 4; ++j) {
            bb[j].u[0] = BFCVT(bqp[0][j]);
            bb[j].u[1] = BFCVT(bqp[1][j]);
            bb[j].u[2] = BFCVT(bqp[2][j]);
            bb[j].u[3] = BFCVT(bqp[3][j]);
        }
        LGKM(3);
#pragma unroll
        for (int j = 0; j < 4; ++j)
            acc[0][j] = __builtin_amdgcn_mfma_f32_16x16x32_bf16(
                afr[0], bb[j].f, acc[0][j], 0, 0, 0);
        LGKM(2);
#pragma unroll
        for (int j = 0; j < 4; ++j)
            acc[1][j] = __builtin_amdgcn_mfma_f32_16x16x32_bf16(
                afr[1], bb[j].f, acc[1][j], 0, 0, 0);
        LGKM(1);
#pragma unroll
        for (int j = 0; j < 4; ++j)
            acc[2][j] = __builtin_amdgcn_mfma_f32_16x16x32_bf16(
                afr[2], bb[j].f, acc[2][j], 0, 0, 0);
        LGKM(0);
#pragma unroll
        for (int j = 0; j < 4; ++j)
            acc[3][j] = __builtin_amdgcn_mfma_f32_16x16x32_bf16(
                afr[3], bb[j].f, acc[3][j], 0, 0, 0);
    };

    // prologue: depth-1 prefetch
    stage(0, 0);

    int cur = 0;
    for (int t = 0; t < NTt; ++t) {
        int pbuf = cur + 1; if (pbuf >= 3) pbuf -= 3;
        if (t + 1 < NTt) {
            stage(t + 1, pbuf);
            VMW(4);
        } else {
            VMW(0);
        }
        __builtin_amdgcn_s_barrier();     // single barrier (3-buf, depth-1)
        __builtin_amdgcn_sched_barrier(0);
        compute(cur);
        ++cur; if (cur >= 3) cur -= 3;
    }

    // epilogue: lane's cols = n0 + wn*64 + 4*l4 + j  (consecutive in j)
    const int ce = n0 + wn * 64 + 4 * l4;
    const float4 scv = *reinterpret_cast<const float4*>(&scales[ce]);
    const float4 zv  = *reinterpret_cast<const float4*>(&zeroes[ce]);
    const float sc[4] = {scv.x, scv.y, scv.z, scv.w};
    const float zp[4] = {zv.x + 32.0f * scv.x, zv.y + 32.0f * scv.y,
                         zv.z + 32.0f * scv.z, zv.w + 32.0f * scv.w};

    if (mode == 2) {
        // --- all splits: write bf16 partial into slot sp
        ushort* pb = partial + (size_t)sp * MN;
#pragma unroll
        for (int mf = 0; mf < 4; ++mf)
#pragma unroll
            for (int jr = 0; jr < 4; ++jr) {
                int m = m0 + wm * 64 + mf * 16 + c * 4 + jr;
                ushort4 o;
                o.x = (ushort)f2bf_rn(sc[0] * acc[mf][0][jr]);
                o.y = (ushort)f2bf_rn(sc[1] * acc[mf][1][jr]);
                o.z = (ushort)f2bf_rn(sc[2] * acc[mf][2][jr]);
                o.w = (ushort)f2bf_rn(sc[3] * acc[mf][3][jr]);
                *reinterpret_cast<ushort4*>(&pb[(size_t)m * N_DIM + ce]) = o;
            }
        __syncthreads();                   // all writes issued+drained
        if (tid == 0) {
            __threadfence();               // device-scope release
            s_done = atomicAdd(&cnt[nb * 2 + mb], 1u);
        }
        __syncthreads();
        if (s_done == 3u) {                // last block: fixed-order sum -> out
            __threadfence();               // acquire
#pragma unroll
            for (int mf = 0; mf < 4; ++mf) {
                const float4 rs = *reinterpret_cast<const float4*>(
                    &rowsum[m0 + wm * 64 + mf * 16 + c * 4]);
                const float rsa[4] = {rs.x, rs.y, rs.z, rs.w};
#pragma unroll
                for (int jr = 0; jr < 4; ++jr) {
                    int m = m0 + wm * 64 + mf * 16 + c * 4 + jr;
                    size_t base = (size_t)m * N_DIM + ce;
                    ushort4 p0 = *reinterpret_cast<const ushort4*>(&partial[0 * MN + base]);
                    ushort4 p1 = *reinterpret_cast<const ushort4*>(&partial[1 * MN + base]);
                    ushort4 p2 = *reinterpret_cast<const ushort4*>(&partial[2 * MN + base]);
                    ushort4 p3 = *reinterpret_cast<const ushort4*>(&partial[3 * MN + base]);
                    float4 o;
                    o.x = bf2f(p0.x) + bf2f(p1.x) + bf2f(p2.x) + bf2f(p3.x) - zp[0] * rsa[jr];
                    o.y = bf2f(p0.y) + bf2f(p1.y) + bf2f(p2.y) + bf2f(p3.y) - zp[1] * rsa[jr];
                    o.z = bf2f(p0.z) + bf2f(p1.z) + bf2f(p2.z) + bf2f(p3.z) - zp[2] * rsa[jr];
                    o.w = bf2f(p0.w) + bf2f(p1.w) + bf2f(p2.w) + bf2f(p3.w) - zp[3] * rsa[jr];
                    *reinterpret_cast<float4*>(&out[base]) = o;
                }
            }
        }
    } else if (mode == 0 || sp == 0) {
#pragma unroll
        for (int mf = 0; mf < 4; ++mf) {
            const float4 rs = *reinterpret_cast<const float4*>(
                &rowsum[m0 + wm * 64 + mf * 16 + c * 4]);
            const float rsa[4] = {rs.x, rs.y, rs.z, rs.w};
#pragma unroll
            for (int jr = 0; jr < 4; ++jr) {
                int m = m0 + wm * 64 + mf * 16 + c * 4 + jr;
                float4 o;
                o.x = sc[0] * acc[mf][0][jr] - zp[0] * rsa[jr];
                o.y = sc[1] * acc[mf][1][jr] - zp[1] * rsa[jr];
                o.z = sc[2] * acc[mf][2][jr] - zp[2] * rsa[jr];
                o.w = sc[3] * acc[mf][3][jr] - zp[3] * rsa[jr];
                *reinterpret_cast<float4*>(&out[(size_t)m * N_DIM + ce]) = o;
            }
        }
    } else {
        ushort* pb = partial + (size_t)(sp - 1) * MN;
#pragma unroll
        for (int mf = 0; mf < 4; ++mf)
#pragma unroll
            for (int jr = 0; jr < 4; ++jr) {
                int m = m0 + wm * 64 + mf * 16 + c * 4 + jr;
                ushort4 o;
                o.x = (ushort)f2bf_rn(sc[0] * acc[mf][0][jr]);
                o.y = (ushort)f2bf_rn(sc[1] * acc[mf][1][jr]);
                o.z = (ushort)f2bf_rn(sc[2] * acc[mf][2][jr]);
                o.w = (ushort)f2bf_rn(sc[3] * acc[mf][3][jr]);
                *reinterpret_cast<ushort4*>(&pb[(size_t)m * N_DIM + ce]) = o;
            }
    }
}

// Kernel 3 (mode-1 fallback): out += bf16-partials p0+p1+p2.
__global__ __launch_bounds__(256) void reduce_kernel(float* __restrict__ out,
                                                     const ushort* __restrict__ partial) {
    size_t i = ((size_t)blockIdx.x * 256 + threadIdx.x) * 4;
    float4 o = *reinterpret_cast<float4*>(out + i);
    ushort4 a = *reinterpret_cast<const ushort4*>(partial + i);
    ushort4 b = *reinterpret_cast<const ushort4*>(partial + MN + i);
    ushort4 d = *reinterpret_cast<const ushort4*>(partial + 2 * MN + i);
    o.x += bf2f(a.x) + bf2f(b.x) + bf2f(d.x);
    o.y += bf2f(a.y) + bf2f(b.y) + bf2f(d.y);
    o.z += bf2f(a.z) + bf2f(b.z) + bf2f(d.z);
    o.w += bf2f(a.w) + bf2f(b.w) + bf2f(d.w);
    *reinterpret_cast<float4*>(out + i) = o;
}

extern "C" void kernel_launch(void* const* d_in, const int* in_sizes, int n_in,
                              void* d_out, int out_size, void* d_ws, size_t ws_size,
                              hipStream_t stream) {
    const float* x      = (const float*)d_in[0];
    const int*   qw     = (const int*)d_in[1];
    const float* scales = (const float*)d_in[2];
    const float* zeroes = (const float*)d_in[3];
    float* out = (float*)d_out;

    const size_t XBF_BYTES = (size_t)M_DIM * K_DIM * 2;   // 2 MB
    const size_t RS_OFF    = XBF_BYTES;                    // 1 KB
    const size_t P_OFF     = XBF_BYTES + 4096;
    const size_t P3_BYTES  = 3 * MN * 2;                   // 16.9 MB
    const size_t P4_BYTES  = 4 * MN * 2;                   // 22.5 MB
    const size_t CNT_OFF   = P_OFF + P4_BYTES;
    const size_t CNT_BYTES = 256 * 4;

    ushort* xbf    = (ushort*)d_ws;
    float*  rowsum = (float*)((char*)d_ws + RS_OFF);
    ushort* part   = (ushort*)((char*)d_ws + P_OFF);
    u32*    cnt    = (u32*)((char*)d_ws + CNT_OFF);

    int mode;
    if (ws_size >= CNT_OFF + CNT_BYTES)      mode = 2;   // fused reduction
    else if (ws_size >= P_OFF + P3_BYTES)    mode = 1;   // r23 fallback
    else                                     mode = 0;   // no split

    prep_kernel<<<M_DIM, 256, 0, stream>>>(x, xbf, rowsum);
    if (mode == 2) {
        init_kernel<<<1, 256, 0, stream>>>(cnt);
        gemm_kernel<<<688, 256, 0, stream>>>(qw, scales, zeroes, xbf, rowsum,
                                             out, part, cnt, 2);
    } else if (mode == 1) {
        gemm_kernel<<<688, 256, 0, stream>>>(qw, scales, zeroes, xbf, rowsum,
                                             out, part, nullptr, 1);
        reduce_kernel<<<(int)(MN / (256 * 4)), 256, 0, stream>>>(out, part);
    } else {
        gemm_kernel<<<172, 256, 0, stream>>>(qw, scales, zeroes, xbf, rowsum,
                                             out, nullptr, nullptr, 0);
    }
}

// Round 25
// 48.481 us; speedup vs baseline: 2.1086x; 2.1086x over previous
//
#include <hip/hip_runtime.h>
#include <stdint.h>

#define K_DIM 4096
#define N_DIM 11008
#define M_DIM 256

typedef uint32_t u32;
using frag_ab = __attribute__((ext_vector_type(8))) short;   // 8 bf16
using frag_cd = __attribute__((ext_vector_type(4))) float;   // 4 f32
using u32x4   = __attribute__((ext_vector_type(4))) uint32_t;

typedef __attribute__((address_space(3))) const char lds_cc;

#define DSR128(dst, addr, off)                                       \
    asm volatile("ds_read_b128 %0, %1 offset:" #off                  \
                 : "=&v"(dst) : "v"(addr))
#define LGKM(n) do { asm volatile("s_waitcnt lgkmcnt(" #n ")" ::: "memory"); \
                     __builtin_amdgcn_sched_barrier(0); } while (0)
#define VMW(n) asm volatile("s_waitcnt vmcnt(" #n ")" ::: "memory")

__device__ __forceinline__ u32 f2bf_rn(float f) {
    u32 u = __builtin_bit_cast(u32, f);
    return (u + 0x7FFFu + ((u >> 16) & 1u)) >> 16;   // round-to-nearest-even
}
__device__ __forceinline__ float bf2f(u32 b) {
    return __builtin_bit_cast(float, b << 16);
}
__device__ __forceinline__ void gll16(const void* g, void* l) {
    __builtin_amdgcn_global_load_lds(
        (const __attribute__((address_space(1))) u32*)g,
        (__attribute__((address_space(3))) u32*)l, 16, 0, 0);
}

// bf16(32+v) = 0x4200 | (v<<2); q*0x4004 = q<<14|q<<2 -> packed bf16x2.
#define BFCVT(q) ((u32)((__mul24((int)(q), 0x4004) & 0x003C003C) | 0x42004200))

// Kernel 1: x f32 -> bf16 (RN) + per-row sums of the ROUNDED values.
__global__ __launch_bounds__(256) void prep_kernel(const float* __restrict__ x,
                                                   ushort* __restrict__ xbf,
                                                   float* __restrict__ rowsum) {
    const int row = blockIdx.x;
    const int tid = threadIdx.x;
    const float* xr = x + (size_t)row * K_DIM;
    ushort* br = xbf + (size_t)row * K_DIM;
    float s = 0.0f;
#pragma unroll
    for (int p = 0; p < 4; ++p) {
        int i = p * 1024 + tid * 4;
        float4 v = *reinterpret_cast<const float4*>(xr + i);
        u32 b0 = f2bf_rn(v.x), b1 = f2bf_rn(v.y), b2 = f2bf_rn(v.z), b3 = f2bf_rn(v.w);
        uint2 o;
        o.x = b0 | (b1 << 16);
        o.y = b2 | (b3 << 16);
        *reinterpret_cast<uint2*>(br + i) = o;
        s += bf2f(b0) + bf2f(b1) + bf2f(b2) + bf2f(b3);
    }
#pragma unroll
    for (int off = 32; off > 0; off >>= 1) s += __shfl_down(s, off, 64);
    __shared__ float wsum[4];
    if ((tid & 63) == 0) wsum[tid >> 6] = s;
    __syncthreads();
    if (tid == 0) rowsum[row] = wsum[0] + wsum[1] + wsum[2] + wsum[3];
}

// Kernel 2: best-measured structure (r23, 48.38 us total).  BM=128, BN=128,
// BK=32, split-K=4, grid 688 (8*86), 4 waves (2m x 2n), wave tile 64x64,
// 48 KB triple-buffered LDS -> 3 blocks/CU.  Single barrier per tile
// (depth-1 prefetch: stage target (t+1)%3 distinct from compute t%3 and
// laggard (t-1)%3).  Col-group B fragments (frag j = cols==j mod 4) make
// each lane's per-p B needs one contiguous 16B chunk -> B read as 4x
// ds_read_b128.  Stepped lgkm overlaps BFCVT/MFMA with remaining reads.
__global__ __launch_bounds__(256, 3) void gemm_kernel(const int* __restrict__ qw,
                                                      const float* __restrict__ scales,
                                                      const float* __restrict__ zeroes,
                                                      const ushort* __restrict__ xbf,
                                                      const float* __restrict__ rowsum,
                                                      float* __restrict__ out,
                                                      ushort* __restrict__ partial,
                                                      int split4) {
    // A tile: [m 0..127][chunk 0..3 of 16B], stored chunk' = chunk ^ ((m>>1)&3)
    // B tile: chunk ci = row*32 + wn*16 + l4 holds B[row][wn*64+4*l4 .. +3]
    __shared__ uint4 Alds[3][512];    // 3 x 8 KB
    __shared__ u32   Blds[3][2048];   // 3 x 8 KB

    const u32* qwu = (const u32*)qw;
    const int tid  = threadIdx.x;
    const int lane = tid & 63;
    const int wid  = tid >> 6;
    const int l4   = lane & 15;
    const int c    = lane >> 4;

    // XCD-bijective swizzle (688 = 8*86): the 8 blocks (2mb x 4sp) of one
    // n-strip are consecutive wg -> same XCD L2 for the shared B slice.
    const int orig = blockIdx.x;
    int nb, mb, sp, NTt;
    if (split4) {
        int wg = (orig & 7) * 86 + (orig >> 3);
        nb = wg >> 3; sp = (wg >> 1) & 3; mb = wg & 1; NTt = 32;
    } else {
        nb = orig >> 1; mb = orig & 1; sp = 0; NTt = 128;
    }
    const int n0 = nb * 128;
    const int m0 = mb * 128;
    const int wm = wid >> 1;
    const int wn = wid & 1;

    // ---- A staging (r22-verified pre-swizzle)
    const ushort* asrc[2];
#pragma unroll
    for (int j = 0; j < 2; ++j)
        asrc[j] = xbf + (size_t)(m0 + j * 64 + wid * 16 + (lane >> 2)) * K_DIM +
                  sp * 1024 + 8 * ((lane & 3) ^ ((lane >> 3) & 3));
    // ---- B staging: round r stages chunk ci = r*256 + wid*64 + lane;
    //      row = ci>>5; Global cols (4*(lane&15) .. +3) contiguous -> gll16.
    const u32* bsrc[2];
#pragma unroll
    for (int r = 0; r < 2; ++r)
        bsrc[r] = qwu + (size_t)(sp * 512 + r * 8 + wid * 2 + (lane >> 5)) * N_DIM +
                  n0 + ((lane >> 4) & 1) * 64 + 4 * (lane & 15);

    // ---- LDS read byte-offsets
    const u32 aoff = (u32)((wm * 64 + l4) * 64 + ((c ^ ((l4 >> 1) & 3)) << 4));
    const u32 boff = (u32)(c * 2048 + wn * 256 + l4 * 16);   // p stride = 512B

    frag_cd acc[4][4];   // [mf][col-group j]
#pragma unroll
    for (int i = 0; i < 4; ++i)
#pragma unroll
        for (int j = 0; j < 4; ++j)
            acc[i][j] = (frag_cd){0.f, 0.f, 0.f, 0.f};

    auto stage = [&](int t, int buf) {      // 4 x global_load_lds(16B)
#pragma unroll
        for (int j = 0; j < 2; ++j)
            gll16(asrc[j] + (size_t)t * 32, &Alds[buf][j * 256 + wid * 64]);
#pragma unroll
        for (int r = 0; r < 2; ++r)
            gll16(bsrc[r] + (size_t)t * 16 * N_DIM,
                  &Blds[buf][(r * 256 + wid * 64) * 4]);
    };

    auto compute = [&](int buf) {
        lds_cc* Ab = (lds_cc*)&Alds[buf][0];
        lds_cc* Bb = (lds_cc*)&Blds[buf][0];
        u32x4 bqp[4];
        DSR128(bqp[0], Bb + boff, 0);
        DSR128(bqp[1], Bb + boff, 512);
        DSR128(bqp[2], Bb + boff, 1024);
        DSR128(bqp[3], Bb + boff, 1536);
        frag_ab afr[4];
        DSR128(afr[0], Ab + aoff, 0);
        DSR128(afr[1], Ab + aoff, 1024);
        DSR128(afr[2], Ab + aoff, 2048);
        DSR128(afr[3], Ab + aoff, 3072);
        LGKM(4);   // B0..3 landed (in-order DS completion)
        union { frag_ab f; u32 u[4]; } bb[4];
#pragma unroll
        for (int j = 0; j < 4; ++j) {
            bb[j].u[0] = BFCVT(bqp[0][j]);
            bb[j].u[1] = BFCVT(bqp[1][j]);
            bb[j].u[2] = BFCVT(bqp[2][j]);
            bb[j].u[3] = BFCVT(bqp[3][j]);
        }
        LGKM(3);
#pragma unroll
        for (int j = 0; j < 4; ++j)
            acc[0][j] = __builtin_amdgcn_mfma_f32_16x16x32_bf16(
                afr[0], bb[j].f, acc[0][j], 0, 0, 0);
        LGKM(2);
#pragma unroll
        for (int j = 0; j < 4; ++j)
            acc[1][j] = __builtin_amdgcn_mfma_f32_16x16x32_bf16(
                afr[1], bb[j].f, acc[1][j], 0, 0, 0);
        LGKM(1);
#pragma unroll
        for (int j = 0; j < 4; ++j)
            acc[2][j] = __builtin_amdgcn_mfma_f32_16x16x32_bf16(
                afr[2], bb[j].f, acc[2][j], 0, 0, 0);
        LGKM(0);
#pragma unroll
        for (int j = 0; j < 4; ++j)
            acc[3][j] = __builtin_amdgcn_mfma_f32_16x16x32_bf16(
                afr[3], bb[j].f, acc[3][j], 0, 0, 0);
    };

    // prologue: depth-1 prefetch
    stage(0, 0);

    int cur = 0;
    for (int t = 0; t < NTt; ++t) {
        int pbuf = cur + 1; if (pbuf >= 3) pbuf -= 3;
        if (t + 1 < NTt) {
            stage(t + 1, pbuf);
            VMW(4);                       // tile t's 4 loads landed; t+1 in flight
        } else {
            VMW(0);
        }
        __builtin_amdgcn_s_barrier();     // single barrier per tile (3-buf, depth-1)
        __builtin_amdgcn_sched_barrier(0);
        compute(cur);
        ++cur; if (cur >= 3) cur -= 3;
    }

    // epilogue: lane's cols = n0 + wn*64 + 4*l4 + j  (consecutive in j)
    const int ce = n0 + wn * 64 + 4 * l4;
    const float4 scv = *reinterpret_cast<const float4*>(&scales[ce]);
    const float4 zv  = *reinterpret_cast<const float4*>(&zeroes[ce]);
    const float sc[4] = {scv.x, scv.y, scv.z, scv.w};
    const float zp[4] = {zv.x + 32.0f * scv.x, zv.y + 32.0f * scv.y,
                         zv.z + 32.0f * scv.z, zv.w + 32.0f * scv.w};
    if (sp == 0) {
#pragma unroll
        for (int mf = 0; mf < 4; ++mf) {
            const float4 rs = *reinterpret_cast<const float4*>(
                &rowsum[m0 + wm * 64 + mf * 16 + c * 4]);
            const float rsa[4] = {rs.x, rs.y, rs.z, rs.w};
#pragma unroll
            for (int jr = 0; jr < 4; ++jr) {
                int m = m0 + wm * 64 + mf * 16 + c * 4 + jr;
                float4 o;
                o.x = sc[0] * acc[mf][0][jr] - zp[0] * rsa[jr];
                o.y = sc[1] * acc[mf][1][jr] - zp[1] * rsa[jr];
                o.z = sc[2] * acc[mf][2][jr] - zp[2] * rsa[jr];
                o.w = sc[3] * acc[mf][3][jr] - zp[3] * rsa[jr];
                *reinterpret_cast<float4*>(&out[(size_t)m * N_DIM + ce]) = o;
            }
        }
    } else {
        ushort* pb = partial + (size_t)(sp - 1) * M_DIM * N_DIM;
#pragma unroll
        for (int mf = 0; mf < 4; ++mf)
#pragma unroll
            for (int jr = 0; jr < 4; ++jr) {
                int m = m0 + wm * 64 + mf * 16 + c * 4 + jr;
                ushort4 o;
                o.x = (ushort)f2bf_rn(sc[0] * acc[mf][0][jr]);
                o.y = (ushort)f2bf_rn(sc[1] * acc[mf][1][jr]);
                o.z = (ushort)f2bf_rn(sc[2] * acc[mf][2][jr]);
                o.w = (ushort)f2bf_rn(sc[3] * acc[mf][3][jr]);
                *reinterpret_cast<ushort4*>(&pb[(size_t)m * N_DIM + ce]) = o;
            }
    }
}

// Kernel 3: out += bf16-partials p0+p1+p2.  Exact cover: 2752 blocks *
// 256 threads * 4 floats = 2,818,048 = 256*11008.
__global__ __launch_bounds__(256) void reduce_kernel(float* __restrict__ out,
                                                     const ushort* __restrict__ partial) {
    const size_t NTOT = (size_t)M_DIM * N_DIM;
    size_t i = ((size_t)blockIdx.x * 256 + threadIdx.x) * 4;
    float4 o = *reinterpret_cast<float4*>(out + i);
    ushort4 a = *reinterpret_cast<const ushort4*>(partial + i);
    ushort4 b = *reinterpret_cast<const ushort4*>(partial + NTOT + i);
    ushort4 d = *reinterpret_cast<const ushort4*>(partial + 2 * NTOT + i);
    o.x += bf2f(a.x) + bf2f(b.x) + bf2f(d.x);
    o.y += bf2f(a.y) + bf2f(b.y) + bf2f(d.y);
    o.z += bf2f(a.z) + bf2f(b.z) + bf2f(d.z);
    o.w += bf2f(a.w) + bf2f(b.w) + bf2f(d.w);
    *reinterpret_cast<float4*>(out + i) = o;
}

extern "C" void kernel_launch(void* const* d_in, const int* in_sizes, int n_in,
                              void* d_out, int out_size, void* d_ws, size_t ws_size,
                              hipStream_t stream) {
    const float* x      = (const float*)d_in[0];
    const int*   qw     = (const int*)d_in[1];
    const float* scales = (const float*)d_in[2];
    const float* zeroes = (const float*)d_in[3];
    float* out = (float*)d_out;

    const size_t XBF_BYTES = (size_t)M_DIM * K_DIM * 2;        // 2 MB
    const size_t RS_OFF    = XBF_BYTES;                         // 1 KB
    const size_t P_OFF     = XBF_BYTES + 4096;
    const size_t P_BYTES   = (size_t)3 * M_DIM * N_DIM * 2;     // 16.9 MB bf16

    ushort* xbf    = (ushort*)d_ws;
    float*  rowsum = (float*)((char*)d_ws + RS_OFF);
    ushort* part   = (ushort*)((char*)d_ws + P_OFF);

    const bool split4 = ws_size >= P_OFF + P_BYTES;

    prep_kernel<<<M_DIM, 256, 0, stream>>>(x, xbf, rowsum);
    if (split4) {
        gemm_kernel<<<688, 256, 0, stream>>>(qw, scales, zeroes, xbf, rowsum,
                                             out, part, 1);
        reduce_kernel<<<(M_DIM * N_DIM) / (256 * 4), 256, 0, stream>>>(out, part);
    } else {
        gemm_kernel<<<172, 256, 0, stream>>>(qw, scales, zeroes, xbf, rowsum,
                                             out, nullptr, 0);
    }
}

// Round 26
// 47.234 us; speedup vs baseline: 2.1643x; 1.0264x over previous
//
#include <hip/hip_runtime.h>
#include <stdint.h>

#define K_DIM 4096
#define N_DIM 11008
#define M_DIM 256
#define MN ((size_t)M_DIM * N_DIM)

typedef uint32_t u32;
using frag_ab = __attribute__((ext_vector_type(8))) short;   // 8 bf16
using frag_cd = __attribute__((ext_vector_type(4))) float;   // 4 f32
using u32x4   = __attribute__((ext_vector_type(4))) uint32_t;

typedef __attribute__((address_space(3))) const char lds_cc;

#define DSR128(dst, addr, off)                                       \
    asm volatile("ds_read_b128 %0, %1 offset:" #off                  \
                 : "=&v"(dst) : "v"(addr))
#define LGKM(n) do { asm volatile("s_waitcnt lgkmcnt(" #n ")" ::: "memory"); \
                     __builtin_amdgcn_sched_barrier(0); } while (0)
#define VMW(n) asm volatile("s_waitcnt vmcnt(" #n ")" ::: "memory")

__device__ __forceinline__ u32 f2bf_rn(float f) {
    u32 u = __builtin_bit_cast(u32, f);
    return (u + 0x7FFFu + ((u >> 16) & 1u)) >> 16;   // round-to-nearest-even
}
__device__ __forceinline__ float bf2f(u32 b) {
    return __builtin_bit_cast(float, b << 16);
}
__device__ __forceinline__ void gll16(const void* g, void* l) {
    __builtin_amdgcn_global_load_lds(
        (const __attribute__((address_space(1))) u32*)g,
        (__attribute__((address_space(3))) u32*)l, 16, 0, 0);
}

// bf16(32+v) = 0x4200 | (v<<2); q*0x4004 = q<<14|q<<2 -> packed bf16x2.
#define BFCVT(q) ((u32)((__mul24((int)(q), 0x4004) & 0x003C003C) | 0x42004200))

// Kernel 1: x f32 -> bf16 (RN) + per-row sums of the ROUNDED values.
__global__ __launch_bounds__(256) void prep_kernel(const float* __restrict__ x,
                                                   ushort* __restrict__ xbf,
                                                   float* __restrict__ rowsum) {
    const int row = blockIdx.x;
    const int tid = threadIdx.x;
    const float* xr = x + (size_t)row * K_DIM;
    ushort* br = xbf + (size_t)row * K_DIM;
    float s = 0.0f;
#pragma unroll
    for (int p = 0; p < 4; ++p) {
        int i = p * 1024 + tid * 4;
        float4 v = *reinterpret_cast<const float4*>(xr + i);
        u32 b0 = f2bf_rn(v.x), b1 = f2bf_rn(v.y), b2 = f2bf_rn(v.z), b3 = f2bf_rn(v.w);
        uint2 o;
        o.x = b0 | (b1 << 16);
        o.y = b2 | (b3 << 16);
        *reinterpret_cast<uint2*>(br + i) = o;
        s += bf2f(b0) + bf2f(b1) + bf2f(b2) + bf2f(b3);
    }
#pragma unroll
    for (int off = 32; off > 0; off >>= 1) s += __shfl_down(s, off, 64);
    __shared__ float wsum[4];
    if ((tid & 63) == 0) wsum[tid >> 6] = s;
    __syncthreads();
    if (tid == 0) rowsum[row] = wsum[0] + wsum[1] + wsum[2] + wsum[3];
}

// Kernel 2: r23 gemm loop verbatim (48.38 us total).  Split mode: ALL 4
// splits write bf16 partials (uniform epilogue, 22.5 MB); correction and
// sum move to the bulk-stream reduce (no f32 out write from gemm).
__global__ __launch_bounds__(256, 3) void gemm_kernel(const int* __restrict__ qw,
                                                      const float* __restrict__ scales,
                                                      const float* __restrict__ zeroes,
                                                      const ushort* __restrict__ xbf,
                                                      const float* __restrict__ rowsum,
                                                      float* __restrict__ out,
                                                      ushort* __restrict__ partial,
                                                      int split4) {
    // A tile: [m 0..127][chunk 0..3 of 16B], stored chunk' = chunk ^ ((m>>1)&3)
    // B tile: chunk ci = row*32 + wn*16 + l4 holds B[row][wn*64+4*l4 .. +3]
    __shared__ uint4 Alds[3][512];    // 3 x 8 KB
    __shared__ u32   Blds[3][2048];   // 3 x 8 KB

    const u32* qwu = (const u32*)qw;
    const int tid  = threadIdx.x;
    const int lane = tid & 63;
    const int wid  = tid >> 6;
    const int l4   = lane & 15;
    const int c    = lane >> 4;

    // XCD-bijective swizzle (688 = 8*86)
    const int orig = blockIdx.x;
    int nb, mb, sp, NTt;
    if (split4) {
        int wg = (orig & 7) * 86 + (orig >> 3);
        nb = wg >> 3; sp = (wg >> 1) & 3; mb = wg & 1; NTt = 32;
    } else {
        nb = orig >> 1; mb = orig & 1; sp = 0; NTt = 128;
    }
    const int n0 = nb * 128;
    const int m0 = mb * 128;
    const int wm = wid >> 1;
    const int wn = wid & 1;

    // ---- A staging (r22-verified pre-swizzle)
    const ushort* asrc[2];
#pragma unroll
    for (int j = 0; j < 2; ++j)
        asrc[j] = xbf + (size_t)(m0 + j * 64 + wid * 16 + (lane >> 2)) * K_DIM +
                  sp * 1024 + 8 * ((lane & 3) ^ ((lane >> 3) & 3));
    // ---- B staging (r23-verified): chunk ci = r*256 + wid*64 + lane
    const u32* bsrc[2];
#pragma unroll
    for (int r = 0; r < 2; ++r)
        bsrc[r] = qwu + (size_t)(sp * 512 + r * 8 + wid * 2 + (lane >> 5)) * N_DIM +
                  n0 + ((lane >> 4) & 1) * 64 + 4 * (lane & 15);

    // ---- LDS read byte-offsets
    const u32 aoff = (u32)((wm * 64 + l4) * 64 + ((c ^ ((l4 >> 1) & 3)) << 4));
    const u32 boff = (u32)(c * 2048 + wn * 256 + l4 * 16);   // p stride = 512B

    frag_cd acc[4][4];   // [mf][col-group j]
#pragma unroll
    for (int i = 0; i < 4; ++i)
#pragma unroll
        for (int j = 0; j < 4; ++j)
            acc[i][j] = (frag_cd){0.f, 0.f, 0.f, 0.f};

    auto stage = [&](int t, int buf) {      // 4 x global_load_lds(16B)
#pragma unroll
        for (int j = 0; j < 2; ++j)
            gll16(asrc[j] + (size_t)t * 32, &Alds[buf][j * 256 + wid * 64]);
#pragma unroll
        for (int r = 0; r < 2; ++r)
            gll16(bsrc[r] + (size_t)t * 16 * N_DIM,
                  &Blds[buf][(r * 256 + wid * 64) * 4]);
    };

    auto compute = [&](int buf) {
        lds_cc* Ab = (lds_cc*)&Alds[buf][0];
        lds_cc* Bb = (lds_cc*)&Blds[buf][0];
        u32x4 bqp[4];
        DSR128(bqp[0], Bb + boff, 0);
        DSR128(bqp[1], Bb + boff, 512);
        DSR128(bqp[2], Bb + boff, 1024);
        DSR128(bqp[3], Bb + boff, 1536);
        frag_ab afr[4];
        DSR128(afr[0], Ab + aoff, 0);
        DSR128(afr[1], Ab + aoff, 1024);
        DSR128(afr[2], Ab + aoff, 2048);
        DSR128(afr[3], Ab + aoff, 3072);
        LGKM(4);   // B0..3 landed (in-order DS completion)
        union { frag_ab f; u32 u[4]; } bb[4];
#pragma unroll
        for (int j = 0; j < 4; ++j) {
            bb[j].u[0] = BFCVT(bqp[0][j]);
            bb[j].u[1] = BFCVT(bqp[1][j]);
            bb[j].u[2] = BFCVT(bqp[2][j]);
            bb[j].u[3] = BFCVT(bqp[3][j]);
        }
        LGKM(3);
#pragma unroll
        for (int j = 0; j < 4; ++j)
            acc[0][j] = __builtin_amdgcn_mfma_f32_16x16x32_bf16(
                afr[0], bb[j].f, acc[0][j], 0, 0, 0);
        LGKM(2);
#pragma unroll
        for (int j = 0; j < 4; ++j)
            acc[1][j] = __builtin_amdgcn_mfma_f32_16x16x32_bf16(
                afr[1], bb[j].f, acc[1][j], 0, 0, 0);
        LGKM(1);
#pragma unroll
        for (int j = 0; j < 4; ++j)
            acc[2][j] = __builtin_amdgcn_mfma_f32_16x16x32_bf16(
                afr[2], bb[j].f, acc[2][j], 0, 0, 0);
        LGKM(0);
#pragma unroll
        for (int j = 0; j < 4; ++j)
            acc[3][j] = __builtin_amdgcn_mfma_f32_16x16x32_bf16(
                afr[3], bb[j].f, acc[3][j], 0, 0, 0);
    };

    // prologue: depth-1 prefetch
    stage(0, 0);

    int cur = 0;
    for (int t = 0; t < NTt; ++t) {
        int pbuf = cur + 1; if (pbuf >= 3) pbuf -= 3;
        if (t + 1 < NTt) {
            stage(t + 1, pbuf);
            VMW(4);                       // tile t's 4 loads landed; t+1 in flight
        } else {
            VMW(0);
        }
        __builtin_amdgcn_s_barrier();     // single barrier per tile (3-buf, depth-1)
        __builtin_amdgcn_sched_barrier(0);
        compute(cur);
        ++cur; if (cur >= 3) cur -= 3;
    }

    // epilogue: lane's cols = n0 + wn*64 + 4*l4 + j  (consecutive in j)
    const int ce = n0 + wn * 64 + 4 * l4;
    const float4 scv = *reinterpret_cast<const float4*>(&scales[ce]);
    const float sc[4] = {scv.x, scv.y, scv.z, scv.w};
    if (split4) {
        // uniform: every split writes its bf16 partial slot
        ushort* pb = partial + (size_t)sp * MN;
#pragma unroll
        for (int mf = 0; mf < 4; ++mf)
#pragma unroll
            for (int jr = 0; jr < 4; ++jr) {
                int m = m0 + wm * 64 + mf * 16 + c * 4 + jr;
                ushort4 o;
                o.x = (ushort)f2bf_rn(sc[0] * acc[mf][0][jr]);
                o.y = (ushort)f2bf_rn(sc[1] * acc[mf][1][jr]);
                o.z = (ushort)f2bf_rn(sc[2] * acc[mf][2][jr]);
                o.w = (ushort)f2bf_rn(sc[3] * acc[mf][3][jr]);
                *reinterpret_cast<ushort4*>(&pb[(size_t)m * N_DIM + ce]) = o;
            }
    } else {
        const float4 zv = *reinterpret_cast<const float4*>(&zeroes[ce]);
        const float zp[4] = {zv.x + 32.0f * sc[0], zv.y + 32.0f * sc[1],
                             zv.z + 32.0f * sc[2], zv.w + 32.0f * sc[3]};
#pragma unroll
        for (int mf = 0; mf < 4; ++mf) {
            const float4 rs = *reinterpret_cast<const float4*>(
                &rowsum[m0 + wm * 64 + mf * 16 + c * 4]);
            const float rsa[4] = {rs.x, rs.y, rs.z, rs.w};
#pragma unroll
            for (int jr = 0; jr < 4; ++jr) {
                int m = m0 + wm * 64 + mf * 16 + c * 4 + jr;
                float4 o;
                o.x = sc[0] * acc[mf][0][jr] - zp[0] * rsa[jr];
                o.y = sc[1] * acc[mf][1][jr] - zp[1] * rsa[jr];
                o.z = sc[2] * acc[mf][2][jr] - zp[2] * rsa[jr];
                o.w = sc[3] * acc[mf][3][jr] - zp[3] * rsa[jr];
                *reinterpret_cast<float4*>(&out[(size_t)m * N_DIM + ce]) = o;
            }
        }
    }
}

// Kernel 3: out = p0+p1+p2+p3 - (zero + 32*sc)*rowsum.  Pure producer:
// reads 4 bf16 partials, writes f32 out once.  Exact cover: 2752 blocks *
// 256 threads * 4 floats = 2,818,048 = 256*11008 (11008 % 4 == 0 so each
// 4-float group stays within one row).
__global__ __launch_bounds__(256) void reduce_kernel(float* __restrict__ out,
                                                     const ushort* __restrict__ partial,
                                                     const float* __restrict__ rowsum,
                                                     const float* __restrict__ scales,
                                                     const float* __restrict__ zeroes) {
    size_t i = ((size_t)blockIdx.x * 256 + threadIdx.x) * 4;
    const int m = (int)(i / N_DIM);
    const int n = (int)(i % N_DIM);
    ushort4 a = *reinterpret_cast<const ushort4*>(partial + i);
    ushort4 b = *reinterpret_cast<const ushort4*>(partial + MN + i);
    ushort4 d = *reinterpret_cast<const ushort4*>(partial + 2 * MN + i);
    ushort4 e = *reinterpret_cast<const ushort4*>(partial + 3 * MN + i);
    const float4 scv = *reinterpret_cast<const float4*>(&scales[n]);
    const float4 zv  = *reinterpret_cast<const float4*>(&zeroes[n]);
    const float rs   = rowsum[m];
    float4 o;
    o.x = bf2f(a.x) + bf2f(b.x) + bf2f(d.x) + bf2f(e.x) - (zv.x + 32.0f * scv.x) * rs;
    o.y = bf2f(a.y) + bf2f(b.y) + bf2f(d.y) + bf2f(e.y) - (zv.y + 32.0f * scv.y) * rs;
    o.z = bf2f(a.z) + bf2f(b.z) + bf2f(d.z) + bf2f(e.z) - (zv.z + 32.0f * scv.z) * rs;
    o.w = bf2f(a.w) + bf2f(b.w) + bf2f(d.w) + bf2f(e.w) - (zv.w + 32.0f * scv.w) * rs;
    *reinterpret_cast<float4*>(out + i) = o;
}

extern "C" void kernel_launch(void* const* d_in, const int* in_sizes, int n_in,
                              void* d_out, int out_size, void* d_ws, size_t ws_size,
                              hipStream_t stream) {
    const float* x      = (const float*)d_in[0];
    const int*   qw     = (const int*)d_in[1];
    const float* scales = (const float*)d_in[2];
    const float* zeroes = (const float*)d_in[3];
    float* out = (float*)d_out;

    const size_t XBF_BYTES = (size_t)M_DIM * K_DIM * 2;   // 2 MB
    const size_t RS_OFF    = XBF_BYTES;                    // 1 KB
    const size_t P_OFF     = XBF_BYTES + 4096;
    const size_t P_BYTES   = 4 * MN * 2;                   // 22.5 MB bf16

    ushort* xbf    = (ushort*)d_ws;
    float*  rowsum = (float*)((char*)d_ws + RS_OFF);
    ushort* part   = (ushort*)((char*)d_ws + P_OFF);

    const bool split4 = ws_size >= P_OFF + P_BYTES;

    prep_kernel<<<M_DIM, 256, 0, stream>>>(x, xbf, rowsum);
    if (split4) {
        gemm_kernel<<<688, 256, 0, stream>>>(qw, scales, zeroes, xbf, rowsum,
                                             out, part, 1);
        reduce_kernel<<<(int)(MN / (256 * 4)), 256, 0, stream>>>(
            out, part, rowsum, scales, zeroes);
    } else {
        gemm_kernel<<<172, 256, 0, stream>>>(qw, scales, zeroes, xbf, rowsum,
                                             out, nullptr, 0);
    }
}